// Round 2
// baseline (318.653 us; speedup 1.0000x reference)
//
#include <hip/hip_runtime.h>

// NGNNConv fused single-dispatch kernel.
// out[i,j,:] = m[i,j] * [ (sum_{e: erow[e]=j} m[i,ecol[e]] * X[i,ecol[e],:]) @ W + b*cnt ]
// N=1024, E=8192, IND=OUTD=32, fp32.
//
// R4 design: persistent block-per-CU (256 blocks x 4 i's each).
//  - CSR built ONCE per block in LDS (atomics + scan + scatter) -> kills the
//    4-kernel dispatch chain that was ~55% of wall time.
//  - Cross-round software pipeline: next i's X/mask global loads are issued
//    before the edge loop and stay in flight across barriers. Barriers are
//    raw s_barrier + lgkmcnt(0)-only waits (plain __syncthreads drains
//    vmcnt(0) and would serialize the prefetch).
//  - Proven R3 round structure: XOR-swizzled LDS rows, pre-masked X, mask bit
//    folded into u16 cols (refolded per round; low 10 bits preserved),
//    branchless edge loop, coalesced LDS-staged output stores.

#define NN   1024
#define IND  32
#define OUTD 32
#define EE   8192

typedef __attribute__((ext_vector_type(2))) float f32x2;

// LDS-visibility barrier WITHOUT draining vmcnt (keeps global prefetch in flight).
#define BARRIER_LDS() do { \
    asm volatile("s_waitcnt lgkmcnt(0)" ::: "memory"); \
    __builtin_amdgcn_s_barrier(); \
} while (0)

__global__ __launch_bounds__(1024) void ngnn_fused_kernel(
    const float* __restrict__ X, const int* __restrict__ mask,
    const int* __restrict__ erow, const int* __restrict__ ecol,
    const float* __restrict__ W, const float* __restrict__ b,
    float* __restrict__ out, int n_edges)
{
    extern __shared__ float smem[];
    float*          Xl    = smem;                             // [1024][32] f32, swizzled (128 KB)
    int*            rp    = (int*)(smem + NN * IND);          // [NN+1] row_ptr (4.1 KB)
    float*          maskf = (float*)(rp + NN + 1);            // [NN] (doubles as fill[] in build)
    unsigned short* colsl = (unsigned short*)(maskf + NN);    // [EE] u16 cols (16 KB)

    const int t  = threadIdx.x;
    const int i0 = blockIdx.x * 4;

    // ---- Prefetch round-0 inputs; latency hides under the CSR build ----
    const float4* Xg = (const float4*)(X + (size_t)i0 * NN * IND);
    float4 xv[8];
    #pragma unroll
    for (int it = 0; it < 8; ++it) xv[it] = Xg[it * 1024 + t];
    int mv = mask[(size_t)i0 * NN + t];

    int er[8], ec[8];
    #pragma unroll
    for (int it = 0; it < 8; ++it) {
        const int e = it * 1024 + t;
        er[it] = (e < n_edges) ? (erow[e] & (NN - 1)) : -1;
        ec[it] = (e < n_edges) ? (ecol[e] & (NN - 1)) : 0;
    }

    // ---- CSR build in LDS (Xl region doubles as count scratch) ----
    int* scnt = (int*)smem;
    scnt[t] = 0;
    BARRIER_LDS();
    #pragma unroll
    for (int it = 0; it < 8; ++it)
        if (er[it] >= 0) atomicAdd(&scnt[er[it]], 1);
    BARRIER_LDS();
    const int myv = scnt[t];
    for (int off = 1; off < NN; off <<= 1) {     // Hillis-Steele inclusive scan
        const int a = (t >= off) ? scnt[t - off] : 0;
        BARRIER_LDS();
        scnt[t] += a;
        BARRIER_LDS();
    }
    const int incl = scnt[t];
    int* fill = (int*)maskf;                      // reuse maskf slot during build
    rp[t]   = incl - myv;
    fill[t] = incl - myv;
    if (t == NN - 1) rp[NN] = incl;
    BARRIER_LDS();
    const int e0 = rp[t];
    const int e1 = rp[t + 1];
    #pragma unroll
    for (int it = 0; it < 8; ++it) {
        if (er[it] >= 0) {
            const int pos = atomicAdd(&fill[er[it]], 1);
            colsl[pos] = (unsigned short)ec[it];  // raw col; mask bit folded per round
        }
    }
    BARRIER_LDS();

    // ---- 4 pipelined rounds (i = i0..i0+3) ----
    #pragma unroll 1
    for (int r = 0; r < 4; ++r) {
        const int i = i0 + r;

        // A: publish this round's mask row
        maskf[t] = (float)mv;
        BARRIER_LDS();

        // B: stage pre-masked X into swizzled LDS; refold mask bit into colsl;
        //    then issue NEXT round's global loads (stay in flight through C).
        #pragma unroll
        for (int it = 0; it < 8; ++it) {
            const int f4 = it * 1024 + t;          // float4 index in 128 KB slab
            const int k  = f4 >> 3;                // row
            const int p  = (f4 & 7) ^ (k & 7);     // swizzled slot
            const float m = maskf[k];
            float4 v = xv[it];
            v.x *= m; v.y *= m; v.z *= m; v.w *= m;
            *(float4*)(Xl + (k << 5) + (p << 2)) = v;
        }
        #pragma unroll
        for (int it = 0; it < 8; ++it) {
            const int e = it * 1024 + t;
            if (e < n_edges) {
                const int k = (int)colsl[e] & (NN - 1);   // low bits always the col
                colsl[e] = (unsigned short)(k | ((maskf[k] != 0.f) ? 1024 : 0));
            }
        }
        if (r < 3) {
            const float4* Xgn = (const float4*)(X + (size_t)(i + 1) * NN * IND);
            #pragma unroll
            for (int it = 0; it < 8; ++it) xv[it] = Xgn[it * 1024 + t];
            mv = mask[(size_t)(i + 1) * NN + t];
        }
        BARRIER_LDS();

        // C: branchless edge aggregation + 32x32 matmul
        const float mj = maskf[t];
        f32x2 o2[16];
        if (mj != 0.f) {
            float4 S4[8];
            #pragma unroll
            for (int s = 0; s < 8; ++s) S4[s] = make_float4(0.f, 0.f, 0.f, 0.f);
            int cnt = 0;
            for (int e = e0; e < e1; ++e) {
                const int c = (int)colsl[e];       // ds_read_u16
                const int k = c & (NN - 1);
                cnt += c >> 10;                    // folded mask bit
                const float* rb = Xl + (k << 5);
                const int kb = (k & 7) << 2;
                #pragma unroll
                for (int s = 0; s < 8; ++s) {      // logical seg s at slot s^kb
                    const float4 v = *(const float4*)(rb + ((s << 2) ^ kb));
                    S4[s].x += v.x; S4[s].y += v.y; S4[s].z += v.z; S4[s].w += v.w;
                }
            }
            float S[IND];
            #pragma unroll
            for (int s = 0; s < 8; ++s) {
                S[4*s+0] = S4[s].x; S[4*s+1] = S4[s].y;
                S[4*s+2] = S4[s].z; S[4*s+3] = S4[s].w;
            }
            const float cntf = (float)cnt;
            const f32x2* W2 = (const f32x2*)W;
            const f32x2* b2 = (const f32x2*)b;
            #pragma unroll
            for (int c = 0; c < 16; ++c) o2[c] = b2[c] * cntf;
            #pragma unroll
            for (int d = 0; d < IND; ++d) {
                const float s = S[d];
                #pragma unroll
                for (int c = 0; c < 16; ++c) o2[c] += W2[d * 16 + c] * s;
            }
        } else {
            #pragma unroll
            for (int c = 0; c < 16; ++c) { o2[c].x = 0.f; o2[c].y = 0.f; }
        }
        BARRIER_LDS();   // all Xl reads of this round complete

        // D: stage output row through Xl (swizzled, conflict-free)
        #pragma unroll
        for (int q = 0; q < 8; ++q) {
            const int p = q ^ (t & 7);
            *(float4*)(Xl + (t << 5) + (p << 2)) =
                make_float4(o2[2*q].x, o2[2*q].y, o2[2*q+1].x, o2[2*q+1].y);
        }
        BARRIER_LDS();

        // E: fully coalesced global store (fire-and-forget)
        float4* Og = (float4*)(out + (size_t)i * NN * IND);
        #pragma unroll
        for (int it = 0; it < 8; ++it) {
            const int f4 = it * 1024 + t;
            const int k  = f4 >> 3;
            const int p  = (f4 & 7) ^ (k & 7);
            Og[f4] = *(const float4*)(Xl + (k << 5) + (p << 2));
        }
        BARRIER_LDS();   // Xl free for next round's staging
    }
}

extern "C" void kernel_launch(void* const* d_in, const int* in_sizes, int n_in,
                              void* d_out, int out_size, void* d_ws, size_t ws_size,
                              hipStream_t stream) {
    const float* X    = (const float*)d_in[0];
    const int*   mask = (const int*)d_in[1];
    const int*   erow = (const int*)d_in[2];
    const int*   ecol = (const int*)d_in[3];
    const float* W    = (const float*)d_in[4];
    const float* b    = (const float*)d_in[5];
    float*       out  = (float*)d_out;

    int n_edges = in_sizes[2];
    if (n_edges > EE) n_edges = EE;   // colsl capacity guard

    const size_t shmem = (size_t)NN * IND * sizeof(float)        // Xl    128 KB
                       + (size_t)(NN + 1) * sizeof(int)          // rp    4.1 KB
                       + (size_t)NN * sizeof(float)              // maskf 4 KB
                       + (size_t)EE * sizeof(unsigned short);    // colsl 16 KB
    hipFuncSetAttribute((const void*)ngnn_fused_kernel,
                        hipFuncAttributeMaxDynamicSharedMemorySize, (int)shmem);
    ngnn_fused_kernel<<<NN / 4, 1024, shmem, stream>>>(X, mask, erow, ecol, W, b, out, n_edges);
}